// Round 9
// baseline (195.269 us; speedup 1.0000x reference)
//
#include <hip/hip_runtime.h>

#define NCLS  80
#define SELK  512           // histogram cutoff target rank (survivors ~[512,1000] < CAP)
#define NLVL  3
#define NIMG  8
#define DETS  100
#define CAP   1024          // per-pair collect capacity
#define NSORT 4096          // global sort width (3*CAP padded)
#define NDEC  1024          // ranks decoded for NMS (consumed ~200; 5x margin)
#define HBINS 4096          // q-space bins, 8192-ulp granules
#define NHBLK 16            // hist blocks per (img,level) pair
#define NCBLK 64            // collect blocks per (img,level) pair
#define QBASE 0x3F800000u   // bits of q = 1.0 (q > 1 always)
#define QMAX  0x41C80000u   // bits of 25.0; q < 25  <=>  s > 0.2
#define IMGSZ 2048.0f

// ---------------- helpers ----------------

__device__ __forceinline__ float sigm(float x) {
    if (x >= 0.f) return 1.f / (1.f + expf(-x));
    float e = expf(x);
    return e / (1.f + e);
}

// q = (1+e^-a)(1+e^-b), rounding pinned (identical bits in k_hist and k_collect)
__device__ __forceinline__ unsigned int qbits(float ea, float t1) {
    return __float_as_uint(__fmul_rn(__fadd_rn(1.f, ea), t1));
}

// descending bitonic sort of N u64 keys in LDS (N power of 2, N >= blockDim)
__device__ __forceinline__ void bitonic_desc(unsigned long long* s, int N) {
    for (int k = 2; k <= N; k <<= 1) {
        for (int j = k >> 1; j > 0; j >>= 1) {
            __syncthreads();
            for (int i = threadIdx.x; i < N; i += blockDim.x) {
                int ixj = i ^ j;
                if (ixj > i) {
                    unsigned long long a = s[i], b = s[ixj];
                    bool up = ((i & k) == 0);
                    if (up ? (a < b) : (a > b)) { s[i] = b; s[ixj] = a; }
                }
            }
        }
    }
    __syncthreads();
}

__device__ __forceinline__ void lvl_select(int level,
    const float* c0, const float* c1, const float* c2,
    const float* t0, const float* t1, const float* t2,
    const float** cls, const float** ctr, int* hw) {
    if (level == 0)      { *cls = c0; *ctr = t0; *hw = 4096; }
    else if (level == 1) { *cls = c1; *ctr = t1; *hw = 1024; }
    else                 { *cls = c2; *ctr = t2; *hw = 256; }
}

// ---------------- stage 1: per-block partial histograms of q bits ----------------
// (also zeroes the collect counters; visibility to k_collect via kernel boundary,
//  NO fences: round-7 postmortem showed device-scope __threadfence costs ~170 us)

__global__ void k_hist(const float* c0, const float* c1, const float* c2,
                       const float* t0, const float* t1, const float* t2,
                       unsigned int* parts, unsigned int* counters) {
    int level = blockIdx.z, img = blockIdx.y;
    int pair = img * NLVL + level;
    if (blockIdx.x == 0 && threadIdx.x == 0) counters[pair * 16] = 0;
    const float* cls; const float* ctr; int hw;
    lvl_select(level, c0, c1, c2, t0, t1, t2, &cls, &ctr, &hw);
    int n4 = hw * (NCLS / 4);          // float4 granules; 4 classes share one anchor
    const float4* cl4 = (const float4*)(cls + (size_t)img * hw * NCLS);
    const float* ct = ctr + (size_t)img * hw;
    __shared__ unsigned int h[HBINS];
    for (int i = threadIdx.x; i < HBINS; i += 256) h[i] = 0;
    __syncthreads();
    for (int i = blockIdx.x * 256 + threadIdx.x; i < n4; i += NHBLK * 256) {
        float4 v = cl4[i];
        int a = i / (NCLS / 4);        // 20 float4 per anchor row
        float eb = expf(-ct[a]);
        float t1 = __fadd_rn(1.f, eb);
        #pragma unroll
        for (int k = 0; k < 4; ++k) {
            float x = (k == 0) ? v.x : (k == 1) ? v.y : (k == 2) ? v.z : v.w;
            unsigned int qb = qbits(expf(-x), t1);
            if (qb < QMAX) {
                unsigned int bin = (qb - QBASE) >> 13;
                if (bin > HBINS - 1) bin = HBINS - 1;
                atomicAdd(&h[bin], 1u);
            }
        }
    }
    __syncthreads();
    unsigned int* P = parts + ((size_t)(pair * NHBLK + blockIdx.x)) * HBINS;
    for (int i = threadIdx.x; i < HBINS; i += 256) P[i] = h[i];   // coalesced, no atomics
}

// ---------------- stage 2: merge partials + find cutoff V (rank SELK) ----------------
// q ascending == score descending: scan from bin 0 upward.

__global__ void k_find(const unsigned int* parts, unsigned int* vcut) {
    int pair = blockIdx.x;
    int tid = threadIdx.x;      // 256 threads
    __shared__ unsigned int hb[HBINS];
    __shared__ unsigned int segsum[256];
    __shared__ unsigned int pref[256];
    unsigned int acc[HBINS / 256];
    #pragma unroll
    for (int j = 0; j < HBINS / 256; ++j) acc[j] = 0;
    for (int blk = 0; blk < NHBLK; ++blk) {
        const unsigned int* P = parts + ((size_t)(pair * NHBLK + blk)) * HBINS;
        #pragma unroll
        for (int j = 0; j < HBINS / 256; ++j) acc[j] += P[tid + 256 * j];
    }
    #pragma unroll
    for (int j = 0; j < HBINS / 256; ++j) hb[tid + 256 * j] = acc[j];
    __syncthreads();
    unsigned int seg = 0;
    #pragma unroll
    for (int j = 0; j < 16; ++j) seg += hb[16 * tid + j];   // thread owns bins [16t,16t+16)
    segsum[tid] = seg;
    pref[tid] = seg;
    __syncthreads();
    for (int off = 1; off < 256; off <<= 1) {
        unsigned int v = (tid >= off) ? pref[tid - off] : 0u;
        __syncthreads();
        pref[tid] += v;
        __syncthreads();
    }
    unsigned int incl = pref[tid];
    unsigned int excl = incl - seg;
    if (excl < (unsigned int)SELK && incl >= (unsigned int)SELK) {
        unsigned int cum = excl; int B = HBINS - 1;
        for (int b = 16 * tid; b < 16 * tid + 16; ++b) {
            cum += hb[b];
            if (cum >= (unsigned int)SELK) { B = b; break; }
        }
        vcut[pair] = (B >= HBINS - 1) ? QMAX : (QBASE + ((unsigned int)(B + 1) << 13));
    }
    if (tid == 255 && pref[255] < (unsigned int)SELK)
        vcut[pair] = QMAX;   // fewer than SELK pass threshold: collect all passing
}

// ---------------- stage 3: collect candidates with q_bits < V ----------------
// Survivors staged in LDS (fast local atomics); ONE global atomic per block
// (round-4 postmortem: per-element same-cacheline device atomics serialized ~85 us).
// Key is GLOBALLY comparable: (score_bits << 32) | ~((level<<19)|e) — for equal
// score bits the reference global order is (level asc, flat-index asc), exactly
// what descending-sorting this key yields. Slot order in buf is irrelevant.

__global__ void k_collect(const float* c0, const float* c1, const float* c2,
                          const float* t0, const float* t1, const float* t2,
                          const unsigned int* vcut, unsigned int* counters,
                          unsigned long long* buf) {
    int level = blockIdx.z, img = blockIdx.y;
    const float* cls; const float* ctr; int hw;
    lvl_select(level, c0, c1, c2, t0, t1, t2, &cls, &ctr, &hw);
    int n4 = hw * (NCLS / 4);
    int pair = img * NLVL + level;
    const float4* cl4 = (const float4*)(cls + (size_t)img * hw * NCLS);
    const float* ct = ctr + (size_t)img * hw;
    unsigned int V = vcut[pair];
    __shared__ unsigned long long sbuf[CAP];
    __shared__ unsigned int scnt;
    __shared__ unsigned int sbase;
    if (threadIdx.x == 0) scnt = 0;
    __syncthreads();
    for (int i = blockIdx.x * 256 + threadIdx.x; i < n4; i += NCBLK * 256) {
        float4 v = cl4[i];
        int a = i / (NCLS / 4);
        float cta = ct[a];
        float eb = expf(-cta);
        float t1 = __fadd_rn(1.f, eb);
        #pragma unroll
        for (int k = 0; k < 4; ++k) {
            float x = (k == 0) ? v.x : (k == 1) ? v.y : (k == 2) ? v.z : v.w;
            unsigned int qb = qbits(expf(-x), t1);
            if (qb < V) {
                // exact score, bit-identical to rounds 1-8 (validated absmax 0.0)
                float s = sqrtf(sigm(x) * sigm(cta));
                unsigned int e = (unsigned int)(4 * i + k);          // < 2^19
                unsigned int p = ((unsigned int)level << 19) | e;    // 21-bit tie word
                unsigned int slot = atomicAdd(&scnt, 1u);   // LDS atomic, sparse
                if (slot < CAP)
                    sbuf[slot] = ((unsigned long long)__float_as_uint(s) << 32) | (~p);
            }
        }
    }
    __syncthreads();
    unsigned int cl_n = scnt; if (cl_n > CAP) cl_n = CAP;
    if (threadIdx.x == 0)
        sbase = atomicAdd(&counters[pair * 16], cl_n);      // one global atomic/block
    __syncthreads();
    unsigned int base = sbase;
    for (unsigned int idx = threadIdx.x; idx < cl_n; idx += 256) {
        unsigned int g = base + idx;
        if (g < CAP) buf[(size_t)pair * CAP + g] = sbuf[idx];   // coalesced flush
    }
}

// ---------------- stage 4 (fused): global sort + lazy decode + BATCHED greedy NMS ----------------
// One block per image. Sort all 3 level pools at once (keys are globally
// comparable), decode boxes only for the top NDEC ranks (NMS consumes ~200),
// then the round-6 batched greedy NMS (exact sequential-greedy semantics).

__global__ void __launch_bounds__(1024)
k_merge_nms(const unsigned long long* buf, const unsigned int* counters,
            const float* r0, const float* r1, const float* r2,
            const float* a0, const float* a1, const float* a2,
            float* out) {
    int img = blockIdx.x;
    int tid = threadIdx.x;
    __shared__ unsigned long long S[NSORT];
    __shared__ float4 wbox[NDEC];
    __shared__ int    wlab[NDEC];
    __shared__ float4 sbx[64]; __shared__ float sar[64];
    __shared__ float4 koff[DETS]; __shared__ float karr[DETS];
    __shared__ float4 kb[DETS]; __shared__ float ks[DETS]; __shared__ int kl[DETS];
    __shared__ float4 rb[DETS]; __shared__ int rl[DETS];

    for (int l = 0; l < NLVL; ++l) {
        int pair = img * NLVL + l;
        int c = (int)counters[pair * 16]; if (c > CAP) c = CAP;
        const unsigned long long* B = buf + (size_t)pair * CAP;
        for (int i = tid; i < CAP; i += 1024)
            S[l * CAP + i] = (i < c) ? B[i] : 0ull;
    }
    for (int i = NLVL * CAP + tid; i < NSORT; i += 1024) S[i] = 0ull;
    bitonic_desc(S, NSORT);   // leading __syncthreads inside covers the loads

    // lazy decode of the top NDEC ranks (one thread per rank; gathers anc+reg)
    {
        unsigned long long key = S[tid];
        float4 b4 = make_float4(0.f, 0.f, 0.f, 0.f); int lbv = 0;
        if (key != 0ull) {
            unsigned int p = (~((unsigned int)key)) & 0x1FFFFFu;
            int lvl = (int)(p >> 19);
            unsigned int e = p & 0x7FFFFu;
            int a = (int)(e / NCLS); lbv = (int)(e % NCLS);
            const float* anc; const float* reg; int hw;
            if (lvl == 0)      { anc = a0; reg = r0; hw = 4096; }
            else if (lvl == 1) { anc = a1; reg = r1; hw = 1024; }
            else               { anc = a2; reg = r2; hw = 256; }
            const float* rg = reg + (size_t)img * hw * 4;
            float ax1 = anc[a * 4 + 0], ay1 = anc[a * 4 + 1];
            float ax2 = anc[a * 4 + 2], ay2 = anc[a * 4 + 3];
            float cx = 0.5f * (ax1 + ax2), cy = 0.5f * (ay1 + ay2);
            float w = ax2 - ax1, h = ay2 - ay1;
            float e0 = rg[a * 4 + 0] * w, e1 = rg[a * 4 + 1] * h;
            float e2 = rg[a * 4 + 2] * w, e3 = rg[a * 4 + 3] * h;
            b4.x = fminf(fmaxf(cx - e0, 0.f), IMGSZ);
            b4.y = fminf(fmaxf(cy - e1, 0.f), IMGSZ);
            b4.z = fminf(fmaxf(cx + e2, 0.f), IMGSZ);
            b4.w = fminf(fmaxf(cy + e3, 0.f), IMGSZ);
        }
        wbox[tid] = b4; wlab[tid] = lbv;
    }
    __syncthreads();

    if (tid >= 64) return;   // single wave finishes (batched, short)
    int lane = tid;
    unsigned long long lmask_lt = (lane == 0) ? 0ull : (~0ull >> (64 - lane));

    int kept = 0, ring = 0, r = 0;

    while (kept < DETS && r < NDEC) {
        int rank = r + lane;
        unsigned long long key = (rank < NDEC) ? S[rank] : 0ull;
        unsigned int bits = (unsigned int)(key >> 32);
        unsigned long long pm = __ballot(bits != 0u);   // positives form a prefix (sorted)
        int npos = (pm == ~0ull) ? 64 : (int)__builtin_ctzll(~pm);
        if (npos == 0) break;                           // negatives from rank r onward

        float4 bx = make_float4(0.f, 0.f, 0.f, 0.f); int lb = 0;
        if (lane < npos) { bx = wbox[rank]; lb = wlab[rank]; }
        float off = (float)lb * (IMGSZ + 1.0f);
        float ox1 = bx.x + off, oy1 = bx.y + off;
        float ox2 = bx.z + off, oy2 = bx.w + off;
        float car = (ox2 - ox1) * (oy2 - oy1);
        sbx[lane] = make_float4(ox1, oy1, ox2, oy2);
        sar[lane] = car;        // single wave: program-order LDS, no barrier needed

        // (1) vs previously-kept boxes (broadcast reads, parallel across lanes)
        bool supk = false;
        for (int k2 = 0; k2 < kept; ++k2) {
            float4 kk = koff[k2]; float ka = karr[k2];
            float lx = fmaxf(kk.x, ox1), ly = fmaxf(kk.y, oy1);
            float rx = fminf(kk.z, ox2), ry = fminf(kk.w, oy2);
            float w = fmaxf(rx - lx, 0.f), h = fmaxf(ry - ly, 0.f);
            float inter = w * h;
            supk = supk || (inter / (ka + car - inter) > 0.6f);
        }
        // (2) intra-batch column mask: who among earlier slots suppresses me
        unsigned long long col = 0ull;
        for (int i = 0; i < npos; ++i) {
            float4 c = sbx[i]; float ca = sar[i];
            float lx = fmaxf(c.x, ox1), ly = fmaxf(c.y, oy1);
            float rx = fminf(c.z, ox2), ry = fminf(c.w, oy2);
            float w = fmaxf(rx - lx, 0.f), h = fmaxf(ry - ly, 0.f);
            float inter = w * h;
            if ((inter / (ca + car - inter) > 0.6f) && (i < lane)) col |= (1ull << i);
        }
        // (3) wave-uniform greedy resolve (picks are in increasing slot order)
        unsigned long long undecided = __ballot((lane < npos) && !supk);
        unsigned long long aliveSel = 0ull;
        int capleft = DETS - kept;
        int lastSlot = npos - 1;
        while (undecided) {
            int i = (int)__builtin_ctzll(undecided);
            aliveSel |= (1ull << i);
            undecided &= ~(1ull << i);
            if (--capleft == 0) { lastSlot = i; break; }   // kept hits 100 at slot i
            unsigned long long row = __ballot(((col >> i) & 1ull) != 0ull);
            undecided &= ~row;
        }
        unsigned long long region = (lastSlot >= 63) ? ~0ull : ((1ull << (lastSlot + 1)) - 1ull);
        region &= (npos >= 64) ? ~0ull : ((1ull << npos) - 1ull);
        unsigned long long rejm = region & ~aliveSel;

        if ((aliveSel >> lane) & 1ull) {
            int ki = kept + (int)__popcll(aliveSel & lmask_lt);
            koff[ki] = make_float4(ox1, oy1, ox2, oy2); karr[ki] = car;
            kb[ki] = bx; ks[ki] = __uint_as_float(bits); kl[ki] = lb;
        }
        if ((rejm >> lane) & 1ull) {
            int ri = ring + (int)__popcll(rejm & lmask_lt);
            if (ri < DETS) { rb[ri] = bx; rl[ri] = lb; }
        }
        kept += (int)__popcll(aliveSel);
        ring += (int)__popcll(rejm);
        r += lastSlot + 1;
    }

    // negative / padding fill: remaining ranks in order until ring >= DETS
    while (kept < DETS && ring < DETS && r < NDEC) {
        int rank = r + lane;
        if (rank < NDEC) {
            int ri = ring + lane;
            if (ri < DETS) { rb[ri] = wbox[rank]; rl[ri] = wlab[rank]; }
        }
        int take = NDEC - r; if (take > 64) take = 64;
        ring += take;
        r += 64;
    }

    for (int k = lane; k < DETS; k += 64) {
        float4 bxo; float scv; int lv;
        if (k < kept) { bxo = kb[k]; scv = ks[k]; lv = kl[k]; }
        else { int q = k - kept; bxo = rb[q]; scv = -1.0f; lv = rl[q]; }
        float* ob = out + ((size_t)img * DETS + k) * 4;
        ob[0] = bxo.x; ob[1] = bxo.y; ob[2] = bxo.z; ob[3] = bxo.w;
        out[NIMG * DETS * 4 + img * DETS + k] = scv;
        out[NIMG * DETS * 5 + img * DETS + k] = (float)lv;
    }
}

// ---------------- launch ----------------

extern "C" void kernel_launch(void* const* d_in, const int* in_sizes, int n_in,
                              void* d_out, int out_size, void* d_ws, size_t ws_size,
                              hipStream_t stream) {
    (void)in_sizes; (void)n_in; (void)out_size; (void)ws_size;
    // setup_inputs() dict order: cls0, reg0, ctr0, anc0, cls1, reg1, ctr1, anc1, cls2, reg2, ctr2, anc2
    const float* cls0 = (const float*)d_in[0];
    const float* reg0 = (const float*)d_in[1];
    const float* ctr0 = (const float*)d_in[2];
    const float* anc0 = (const float*)d_in[3];
    const float* cls1 = (const float*)d_in[4];
    const float* reg1 = (const float*)d_in[5];
    const float* ctr1 = (const float*)d_in[6];
    const float* anc1 = (const float*)d_in[7];
    const float* cls2 = (const float*)d_in[8];
    const float* reg2 = (const float*)d_in[9];
    const float* ctr2 = (const float*)d_in[10];
    const float* anc2 = (const float*)d_in[11];
    float* out = (float*)d_out;
    char* ws = (char*)d_ws;

    // workspace layout (bytes)
    const size_t OFF_PARTS = 0;          // 24*16*4096*4 = 6,291,456 (fully overwritten)
    const size_t OFF_CNT   = 6291456;    // 24 counters, 64B apart = 1536 (zeroed by k_hist)
    const size_t OFF_VCUT  = 6292992;    // 24*4 -> pad 128
    const size_t OFF_BUF   = 6293120;    // 24*1024*8  = 196,608 -> total 6,489,728

    unsigned int* parts = (unsigned int*)(ws + OFF_PARTS);
    unsigned int* cnt   = (unsigned int*)(ws + OFF_CNT);
    unsigned int* vcut  = (unsigned int*)(ws + OFF_VCUT);
    unsigned long long* buf  = (unsigned long long*)(ws + OFF_BUF);

    k_hist<<<dim3(NHBLK, NIMG, NLVL), 256, 0, stream>>>(
        cls0, cls1, cls2, ctr0, ctr1, ctr2, parts, cnt);
    k_find<<<24, 256, 0, stream>>>(parts, vcut);
    k_collect<<<dim3(NCBLK, NIMG, NLVL), 256, 0, stream>>>(
        cls0, cls1, cls2, ctr0, ctr1, ctr2, vcut, cnt, buf);
    k_merge_nms<<<NIMG, 1024, 0, stream>>>(buf, cnt, reg0, reg1, reg2,
                                           anc0, anc1, anc2, out);
}

// Round 10
// 177.649 us; speedup vs baseline: 1.0992x; 1.0992x over previous
//
#include <hip/hip_runtime.h>

#define NCLS  80
#define SELK  512           // histogram cutoff target rank (survivors ~[512,650] < CAP)
#define NLVL  3
#define NIMG  8
#define DETS  100
#define CAP   1024          // per-pair collect capacity == sort segment width
#define NDEC  1024          // ranks decoded for NMS (consumed ~200-300; big margin)
#define HBINS 4096          // q-space bins, 8192-ulp granules
#define NHBLK 16            // hist blocks per (img,level) pair
#define NCBLK 16            // collect blocks per (img,level) pair
#define QBASE 0x3F800000u   // bits of q = 1.0 (q > 1 always)
#define QMAX  0x41C80000u   // bits of 25.0; q < 25  <=>  s > 0.2
#define IMGSZ 2048.0f

// ---------------- helpers ----------------

__device__ __forceinline__ float sigm(float x) {
    if (x >= 0.f) return 1.f / (1.f + expf(-x));
    float e = expf(x);
    return e / (1.f + e);
}

// q = (1+e^-a)(1+e^-b), rounding pinned (identical bits in k_hist and k_collect)
__device__ __forceinline__ unsigned int qbits(float ea, float t1) {
    return __float_as_uint(__fmul_rn(__fadd_rn(1.f, ea), t1));
}

__device__ __forceinline__ void lvl_select(int level,
    const float* c0, const float* c1, const float* c2,
    const float* t0, const float* t1, const float* t2,
    const float** cls, const float** ctr, int* hw) {
    if (level == 0)      { *cls = c0; *ctr = t0; *hw = 4096; }
    else if (level == 1) { *cls = c1; *ctr = t1; *hw = 1024; }
    else                 { *cls = c2; *ctr = t2; *hw = 256; }
}

// ---------------- stage 1: per-block partial histograms of q bits ----------------
// (also zeroes the collect counters; visibility via kernel boundary, NO fences:
//  round-7 postmortem showed device-scope __threadfence fusion costs ~170 us)

__global__ void k_hist(const float* c0, const float* c1, const float* c2,
                       const float* t0, const float* t1, const float* t2,
                       unsigned int* parts, unsigned int* counters) {
    int level = blockIdx.z, img = blockIdx.y;
    int pair = img * NLVL + level;
    if (blockIdx.x == 0 && threadIdx.x == 0) counters[pair * 16] = 0;
    const float* cls; const float* ctr; int hw;
    lvl_select(level, c0, c1, c2, t0, t1, t2, &cls, &ctr, &hw);
    int n4 = hw * (NCLS / 4);          // float4 granules; 4 classes share one anchor
    const float4* cl4 = (const float4*)(cls + (size_t)img * hw * NCLS);
    const float* ct = ctr + (size_t)img * hw;
    __shared__ unsigned int h[HBINS];
    for (int i = threadIdx.x; i < HBINS; i += 256) h[i] = 0;
    __syncthreads();
    for (int i = blockIdx.x * 256 + threadIdx.x; i < n4; i += NHBLK * 256) {
        float4 v = cl4[i];
        int a = i / (NCLS / 4);        // 20 float4 per anchor row
        float eb = expf(-ct[a]);
        float t1 = __fadd_rn(1.f, eb);
        #pragma unroll
        for (int k = 0; k < 4; ++k) {
            float x = (k == 0) ? v.x : (k == 1) ? v.y : (k == 2) ? v.z : v.w;
            unsigned int qb = qbits(expf(-x), t1);
            if (qb < QMAX) {
                unsigned int bin = (qb - QBASE) >> 13;
                if (bin > HBINS - 1) bin = HBINS - 1;
                atomicAdd(&h[bin], 1u);
            }
        }
    }
    __syncthreads();
    unsigned int* P = parts + ((size_t)(pair * NHBLK + blockIdx.x)) * HBINS;
    for (int i = threadIdx.x; i < HBINS; i += 256) P[i] = h[i];   // coalesced, no atomics
}

// ---------------- stage 2 (fused): in-block cutoff find + collect ----------------
// Each block merges the 16 partials and computes V itself (identical result in
// every block — pure function of parts; ~3 us of redundant L2 reads replaces a
// whole k_find dispatch). Then: survivors staged in LDS (fast local atomics),
// ONE global atomic per block (round-4: per-element device atomics cost ~85 us).
// Key is GLOBALLY comparable: (score_bits << 32) | ~((level<<19)|e) — for equal
// score bits the reference global order is (level asc, flat-index asc), exactly
// what descending-sorting this key yields. Slot order in buf is irrelevant.

__global__ void k_collect(const float* c0, const float* c1, const float* c2,
                          const float* t0, const float* t1, const float* t2,
                          const unsigned int* parts, unsigned int* counters,
                          unsigned long long* buf) {
    int level = blockIdx.z, img = blockIdx.y;
    int pair = img * NLVL + level;
    int tid = threadIdx.x;
    __shared__ unsigned int hb[HBINS];          // 16 KB merged hist
    __shared__ unsigned int segsum[256];
    __shared__ unsigned int pref[256];
    __shared__ unsigned long long sbuf[CAP];    // 8 KB survivor staging
    __shared__ unsigned int scnt, sbase, Vsh;
    if (tid == 0) scnt = 0;
    // merge the 16 partials (coalesced: thread t reads bin t+256j of each)
    {
        unsigned int acc[HBINS / 256];
        #pragma unroll
        for (int j = 0; j < HBINS / 256; ++j) acc[j] = 0;
        for (int blk = 0; blk < NHBLK; ++blk) {
            const unsigned int* P = parts + ((size_t)(pair * NHBLK + blk)) * HBINS;
            #pragma unroll
            for (int j = 0; j < HBINS / 256; ++j) acc[j] += P[tid + 256 * j];
        }
        #pragma unroll
        for (int j = 0; j < HBINS / 256; ++j) hb[tid + 256 * j] = acc[j];
    }
    __syncthreads();
    // scan: q ascending == score descending; find bin bracketing rank SELK
    {
        unsigned int seg = 0;
        #pragma unroll
        for (int j = 0; j < 16; ++j) seg += hb[16 * tid + j];
        segsum[tid] = seg;
        pref[tid] = seg;
        __syncthreads();
        for (int off = 1; off < 256; off <<= 1) {
            unsigned int v = (tid >= off) ? pref[tid - off] : 0u;
            __syncthreads();
            pref[tid] += v;
            __syncthreads();
        }
        unsigned int incl = pref[tid];
        unsigned int excl = incl - segsum[tid];
        if (excl < (unsigned int)SELK && incl >= (unsigned int)SELK) {
            unsigned int cum = excl; int B = HBINS - 1;
            for (int b = 16 * tid; b < 16 * tid + 16; ++b) {
                cum += hb[b];
                if (cum >= (unsigned int)SELK) { B = b; break; }
            }
            Vsh = (B >= HBINS - 1) ? QMAX : (QBASE + ((unsigned int)(B + 1) << 13));
        }
        if (tid == 255 && pref[255] < (unsigned int)SELK)
            Vsh = QMAX;   // fewer than SELK pass threshold: collect all passing
    }
    __syncthreads();
    unsigned int V = Vsh;

    const float* cls; const float* ctr; int hw;
    lvl_select(level, c0, c1, c2, t0, t1, t2, &cls, &ctr, &hw);
    int n4 = hw * (NCLS / 4);
    const float4* cl4 = (const float4*)(cls + (size_t)img * hw * NCLS);
    const float* ct = ctr + (size_t)img * hw;
    for (int i = blockIdx.x * 256 + tid; i < n4; i += NCBLK * 256) {
        float4 v = cl4[i];
        int a = i / (NCLS / 4);
        float cta = ct[a];
        float eb = expf(-cta);
        float t1 = __fadd_rn(1.f, eb);
        #pragma unroll
        for (int k = 0; k < 4; ++k) {
            float x = (k == 0) ? v.x : (k == 1) ? v.y : (k == 2) ? v.z : v.w;
            unsigned int qb = qbits(expf(-x), t1);
            if (qb < V) {
                // exact score, bit-identical to rounds 1-9 (validated absmax 0.0)
                float s = sqrtf(sigm(x) * sigm(cta));
                unsigned int e = (unsigned int)(4 * i + k);          // < 2^19
                unsigned int p = ((unsigned int)level << 19) | e;    // 21-bit tie word
                unsigned int slot = atomicAdd(&scnt, 1u);   // LDS atomic, sparse
                if (slot < CAP)
                    sbuf[slot] = ((unsigned long long)__float_as_uint(s) << 32) | (~p);
            }
        }
    }
    __syncthreads();
    unsigned int cl_n = scnt; if (cl_n > CAP) cl_n = CAP;
    if (tid == 0)
        sbase = atomicAdd(&counters[pair * 16], cl_n);      // one global atomic/block
    __syncthreads();
    unsigned int base = sbase;
    for (unsigned int idx = tid; idx < cl_n; idx += 256) {
        unsigned int g = base + idx;
        if (g < CAP) buf[(size_t)pair * CAP + g] = sbuf[idx];   // coalesced flush
    }
}

// ---------------- stage 3 (fused): segmented sort + merge-path + decode + NMS ----------------
// One block per image. Round-9 postmortem: a monolithic 4096 bitonic at 8 blocks
// is ~80 us (78 barrier phases, 8 CUs). Instead: sort the three 1024-pools
// CONCURRENTLY (segmented bitonic, 55 phases, 3 compare-exchanges/thread/phase),
// then two cheap merge-paths (round-8-validated construct), lazy decode of the
// top NDEC ranks, then the validated batched greedy NMS.

__global__ void __launch_bounds__(1024)
k_merge_nms(const unsigned long long* buf, const unsigned int* counters,
            const float* r0, const float* r1, const float* r2,
            const float* a0, const float* a1, const float* a2,
            float* out) {
    int img = blockIdx.x;
    int tid = threadIdx.x;
    __shared__ unsigned long long S[3 * CAP];     // 24 KB: A|B|C; A-region becomes R
    __shared__ unsigned long long Mbuf[2 * CAP];  // 16 KB: merge(A,B); later wbox
    __shared__ float4 sbx[64]; __shared__ float sar[64];
    __shared__ float4 koff[DETS]; __shared__ float karr[DETS];
    __shared__ float4 kb[DETS]; __shared__ float ks[DETS]; __shared__ int kl[DETS];
    __shared__ float4 rb[DETS]; __shared__ int rl[DETS];
    float4* wbox = (float4*)Mbuf;                 // alias: valid after M is dead
    int*    wlab = (int*)(S + CAP);               // alias: B-region, dead after R

    // load the three pools
    for (int l = 0; l < NLVL; ++l) {
        int pair = img * NLVL + l;
        int c = (int)counters[pair * 16]; if (c > CAP) c = CAP;
        const unsigned long long* B = buf + (size_t)pair * CAP;
        S[l * CAP + tid] = (tid < c) ? B[tid] : 0ull;
    }
    // segmented bitonic: sort all 3 segments concurrently (55 phases)
    for (int k2 = 2; k2 <= CAP; k2 <<= 1) {
        for (int j = k2 >> 1; j > 0; j >>= 1) {
            __syncthreads();
            int i = tid;
            int ixj = i ^ j;
            if (ixj > i) {
                bool up = ((i & k2) == 0);
                #pragma unroll
                for (int seg = 0; seg < NLVL; ++seg) {
                    int base = seg * CAP;
                    unsigned long long a = S[base + i], b = S[base + ixj];
                    if (up ? (a < b) : (a > b)) { S[base + i] = b; S[base + ixj] = a; }
                }
            }
        }
    }
    __syncthreads();
    // merge-path A (1024) + B (1024) -> M (2048), descending, keys unique
    for (int k = tid; k < 2 * CAP; k += 1024) {
        int lo = max(0, k - CAP), hi = min(k, CAP);
        while (lo < hi) {
            int mid = (lo + hi) >> 1;
            if (S[mid] > S[CAP + (k - mid - 1)]) lo = mid + 1; else hi = mid;
        }
        int i = lo, j = k - lo;
        unsigned long long av = (i < CAP) ? S[i] : 0ull;
        unsigned long long bv = (j < CAP) ? S[CAP + j] : 0ull;
        Mbuf[k] = (av > bv) ? av : bv;
    }
    __syncthreads();
    // top-1024 of merge(M (2048), C (1024)) -> R (= A-region, dead)
    {
        int k = tid;
        int lo = max(0, k - CAP), hi = k;   // hi = min(k, 2*CAP) = k
        while (lo < hi) {
            int mid = (lo + hi) >> 1;
            if (Mbuf[mid] > S[2 * CAP + (k - mid - 1)]) lo = mid + 1; else hi = mid;
        }
        int i = lo, j = k - lo;
        unsigned long long mv = (i < 2 * CAP) ? Mbuf[i] : 0ull;
        unsigned long long cv = (j < CAP) ? S[2 * CAP + j] : 0ull;
        unsigned long long rk = (mv > cv) ? mv : cv;
        __syncthreads();                    // all merge reads done before R write
        S[k] = rk;
    }
    __syncthreads();
    // lazy decode of the top NDEC ranks (one thread per rank; gathers anc+reg)
    {
        unsigned long long key = S[tid];
        float4 b4 = make_float4(0.f, 0.f, 0.f, 0.f); int lbv = 0;
        if (key != 0ull) {
            unsigned int p = (~((unsigned int)key)) & 0x1FFFFFu;
            int lvl = (int)(p >> 19);
            unsigned int e = p & 0x7FFFFu;
            int a = (int)(e / NCLS); lbv = (int)(e % NCLS);
            const float* anc; const float* reg; int hw;
            if (lvl == 0)      { anc = a0; reg = r0; hw = 4096; }
            else if (lvl == 1) { anc = a1; reg = r1; hw = 1024; }
            else               { anc = a2; reg = r2; hw = 256; }
            const float* rg = reg + (size_t)img * hw * 4;
            float ax1 = anc[a * 4 + 0], ay1 = anc[a * 4 + 1];
            float ax2 = anc[a * 4 + 2], ay2 = anc[a * 4 + 3];
            float cx = 0.5f * (ax1 + ax2), cy = 0.5f * (ay1 + ay2);
            float w = ax2 - ax1, h = ay2 - ay1;
            float e0 = rg[a * 4 + 0] * w, e1 = rg[a * 4 + 1] * h;
            float e2 = rg[a * 4 + 2] * w, e3 = rg[a * 4 + 3] * h;
            b4.x = fminf(fmaxf(cx - e0, 0.f), IMGSZ);
            b4.y = fminf(fmaxf(cy - e1, 0.f), IMGSZ);
            b4.z = fminf(fmaxf(cx + e2, 0.f), IMGSZ);
            b4.w = fminf(fmaxf(cy + e3, 0.f), IMGSZ);
        }
        wbox[tid] = b4; wlab[tid] = lbv;    // Mbuf / B-region: both dead
    }
    __syncthreads();

    if (tid >= 64) return;   // single wave finishes (batched, short)
    int lane = tid;
    unsigned long long lmask_lt = (lane == 0) ? 0ull : (~0ull >> (64 - lane));

    int kept = 0, ring = 0, r = 0;

    while (kept < DETS && r < NDEC) {
        int rank = r + lane;
        unsigned long long key = (rank < NDEC) ? S[rank] : 0ull;
        unsigned int bits = (unsigned int)(key >> 32);
        unsigned long long pm = __ballot(bits != 0u);   // positives form a prefix (sorted)
        int npos = (pm == ~0ull) ? 64 : (int)__builtin_ctzll(~pm);
        if (npos == 0) break;                           // negatives from rank r onward

        float4 bx = make_float4(0.f, 0.f, 0.f, 0.f); int lb = 0;
        if (lane < npos) { bx = wbox[rank]; lb = wlab[rank]; }
        float off = (float)lb * (IMGSZ + 1.0f);
        float ox1 = bx.x + off, oy1 = bx.y + off;
        float ox2 = bx.z + off, oy2 = bx.w + off;
        float car = (ox2 - ox1) * (oy2 - oy1);
        sbx[lane] = make_float4(ox1, oy1, ox2, oy2);
        sar[lane] = car;        // single wave: program-order LDS, no barrier needed

        // (1) vs previously-kept boxes (broadcast reads, parallel across lanes)
        bool supk = false;
        for (int k2 = 0; k2 < kept; ++k2) {
            float4 kk = koff[k2]; float ka = karr[k2];
            float lx = fmaxf(kk.x, ox1), ly = fmaxf(kk.y, oy1);
            float rx = fminf(kk.z, ox2), ry = fminf(kk.w, oy2);
            float w = fmaxf(rx - lx, 0.f), h = fmaxf(ry - ly, 0.f);
            float inter = w * h;
            supk = supk || (inter / (ka + car - inter) > 0.6f);
        }
        // (2) intra-batch column mask: who among earlier slots suppresses me
        unsigned long long col = 0ull;
        for (int i = 0; i < npos; ++i) {
            float4 c = sbx[i]; float ca = sar[i];
            float lx = fmaxf(c.x, ox1), ly = fmaxf(c.y, oy1);
            float rx = fminf(c.z, ox2), ry = fminf(c.w, oy2);
            float w = fmaxf(rx - lx, 0.f), h = fmaxf(ry - ly, 0.f);
            float inter = w * h;
            if ((inter / (ca + car - inter) > 0.6f) && (i < lane)) col |= (1ull << i);
        }
        // (3) wave-uniform greedy resolve (picks are in increasing slot order)
        unsigned long long undecided = __ballot((lane < npos) && !supk);
        unsigned long long aliveSel = 0ull;
        int capleft = DETS - kept;
        int lastSlot = npos - 1;
        while (undecided) {
            int i = (int)__builtin_ctzll(undecided);
            aliveSel |= (1ull << i);
            undecided &= ~(1ull << i);
            if (--capleft == 0) { lastSlot = i; break; }   // kept hits 100 at slot i
            unsigned long long row = __ballot(((col >> i) & 1ull) != 0ull);
            undecided &= ~row;
        }
        unsigned long long region = (lastSlot >= 63) ? ~0ull : ((1ull << (lastSlot + 1)) - 1ull);
        region &= (npos >= 64) ? ~0ull : ((1ull << npos) - 1ull);
        unsigned long long rejm = region & ~aliveSel;

        if ((aliveSel >> lane) & 1ull) {
            int ki = kept + (int)__popcll(aliveSel & lmask_lt);
            koff[ki] = make_float4(ox1, oy1, ox2, oy2); karr[ki] = car;
            kb[ki] = bx; ks[ki] = __uint_as_float(bits); kl[ki] = lb;
        }
        if ((rejm >> lane) & 1ull) {
            int ri = ring + (int)__popcll(rejm & lmask_lt);
            if (ri < DETS) { rb[ri] = bx; rl[ri] = lb; }
        }
        kept += (int)__popcll(aliveSel);
        ring += (int)__popcll(rejm);
        r += lastSlot + 1;
    }

    // negative / padding fill: remaining ranks in order until ring >= DETS
    while (kept < DETS && ring < DETS && r < NDEC) {
        int rank = r + lane;
        if (rank < NDEC) {
            int ri = ring + lane;
            if (ri < DETS) { rb[ri] = wbox[rank]; rl[ri] = wlab[rank]; }
        }
        int take = NDEC - r; if (take > 64) take = 64;
        ring += take;
        r += 64;
    }

    for (int k = lane; k < DETS; k += 64) {
        float4 bxo; float scv; int lv;
        if (k < kept) { bxo = kb[k]; scv = ks[k]; lv = kl[k]; }
        else { int q = k - kept; bxo = rb[q]; scv = -1.0f; lv = rl[q]; }
        float* ob = out + ((size_t)img * DETS + k) * 4;
        ob[0] = bxo.x; ob[1] = bxo.y; ob[2] = bxo.z; ob[3] = bxo.w;
        out[NIMG * DETS * 4 + img * DETS + k] = scv;
        out[NIMG * DETS * 5 + img * DETS + k] = (float)lv;
    }
}

// ---------------- launch ----------------

extern "C" void kernel_launch(void* const* d_in, const int* in_sizes, int n_in,
                              void* d_out, int out_size, void* d_ws, size_t ws_size,
                              hipStream_t stream) {
    (void)in_sizes; (void)n_in; (void)out_size; (void)ws_size;
    // setup_inputs() dict order: cls0, reg0, ctr0, anc0, cls1, reg1, ctr1, anc1, cls2, reg2, ctr2, anc2
    const float* cls0 = (const float*)d_in[0];
    const float* reg0 = (const float*)d_in[1];
    const float* ctr0 = (const float*)d_in[2];
    const float* anc0 = (const float*)d_in[3];
    const float* cls1 = (const float*)d_in[4];
    const float* reg1 = (const float*)d_in[5];
    const float* ctr1 = (const float*)d_in[6];
    const float* anc1 = (const float*)d_in[7];
    const float* cls2 = (const float*)d_in[8];
    const float* reg2 = (const float*)d_in[9];
    const float* ctr2 = (const float*)d_in[10];
    const float* anc2 = (const float*)d_in[11];
    float* out = (float*)d_out;
    char* ws = (char*)d_ws;

    // workspace layout (bytes)
    const size_t OFF_PARTS = 0;          // 24*16*4096*4 = 6,291,456 (fully overwritten)
    const size_t OFF_CNT   = 6291456;    // 24 counters, 64B apart = 1536 (zeroed by k_hist)
    const size_t OFF_BUF   = 6292992;    // 24*1024*8  = 196,608 -> total 6,489,600

    unsigned int* parts = (unsigned int*)(ws + OFF_PARTS);
    unsigned int* cnt   = (unsigned int*)(ws + OFF_CNT);
    unsigned long long* buf = (unsigned long long*)(ws + OFF_BUF);

    k_hist<<<dim3(NHBLK, NIMG, NLVL), 256, 0, stream>>>(
        cls0, cls1, cls2, ctr0, ctr1, ctr2, parts, cnt);
    k_collect<<<dim3(NCBLK, NIMG, NLVL), 256, 0, stream>>>(
        cls0, cls1, cls2, ctr0, ctr1, ctr2, parts, cnt, buf);
    k_merge_nms<<<NIMG, 1024, 0, stream>>>(buf, cnt, reg0, reg1, reg2,
                                           anc0, anc1, anc2, out);
}